// Round 2
// baseline (386.380 us; speedup 1.0000x reference)
//
#include <hip/hip_runtime.h>
#include <hip/hip_bf16.h>
#include <stdint.h>

#define T_LEN 2048
#define B_SZ  64
#define H_SZ  256
#define NH3   768
#define M_SZ  (T_LEN * B_SZ)   // 131072
#define NC    64
#define TC    32                // T_LEN / NC
#define SCALE_X_F 1.41421356237309515f

typedef __attribute__((ext_vector_type(8))) short short8;
typedef __attribute__((ext_vector_type(4))) float f32x4;

__device__ __forceinline__ float sigmoidf_(float z) {
    return 1.0f / (1.0f + __expf(-z));
}
__device__ __forceinline__ unsigned short f2bf(float f) {
    unsigned u = __float_as_uint(f);
    return (unsigned short)((u + 0x7FFFu + ((u >> 16) & 1u)) >> 16);
}
__device__ __forceinline__ float bf2f(unsigned short s) {
    return __uint_as_float(((unsigned)s) << 16);
}

// ---- x (f32) -> bf16, 8 elems/thread -------------------------------------
__global__ void k_convert_x(const float* __restrict__ x, unsigned short* __restrict__ xb) {
    int i = blockIdx.x * blockDim.x + threadIdx.x;
    const float4* in = (const float4*)x;
    float4 a = in[i * 2];
    float4 b = in[i * 2 + 1];
    short8 o;
    o[0] = (short)f2bf(a.x); o[1] = (short)f2bf(a.y);
    o[2] = (short)f2bf(a.z); o[3] = (short)f2bf(a.w);
    o[4] = (short)f2bf(b.x); o[5] = (short)f2bf(b.y);
    o[6] = (short)f2bf(b.z); o[7] = (short)f2bf(b.w);
    *(short8*)&xb[(size_t)i * 8] = o;
}

// ---- W [256][768] f32 -> Wt [768][256] bf16 ------------------------------
__global__ void k_prep_w(const float* __restrict__ W, unsigned short* __restrict__ Wt) {
    int i = blockIdx.x * 256 + threadIdx.x;   // 196608 total
    int n = i >> 8, k = i & 255;
    Wt[i] = f2bf(W[(size_t)k * NH3 + n]);
}

// ---- bf16 GEMM: C[M,768] = A[M,256] * Bt[768,256]^T, C stored bf16 -------
// 128x128 tile, BK=64, 4 waves (2x2), 16x16x32 MFMA, global_load_lds staging.
__global__ void k_gemm(const unsigned short* __restrict__ A,
                       const unsigned short* __restrict__ Bt,
                       unsigned short* __restrict__ C) {
    __shared__ alignas(16) unsigned short As[128 * 64];
    __shared__ alignas(16) unsigned short Bs[128 * 64];

    int bid = blockIdx.x;
    int mt = bid / 6, nt = bid % 6;   // consecutive blocks share the A tile's L2 lines
    int mbase = mt * 128, nbase = nt * 128;
    int tid = threadIdx.x;
    int w = tid >> 6, l = tid & 63;
    int r16 = l & 15, kg = l >> 4;
    int wr = w >> 1, wc = w & 1;

    f32x4 acc[4][4];
    #pragma unroll
    for (int m = 0; m < 4; ++m)
        #pragma unroll
        for (int n = 0; n < 4; ++n) {
            f32x4 z = {0.f, 0.f, 0.f, 0.f};
            acc[m][n] = z;
        }

    for (int kt = 0; kt < 4; ++kt) {
        int k0 = kt * 64;
        #pragma unroll
        for (int p = 0; p < 4; ++p) {
            int row = w * 32 + p * 8 + (l >> 3);
            int col = (l & 7) * 8;
            const unsigned short* ga = A  + (size_t)(mbase + row) * 256 + k0 + col;
            const unsigned short* gb = Bt + (size_t)(nbase + row) * 256 + k0 + col;
            __builtin_amdgcn_global_load_lds(
                (const __attribute__((address_space(1))) void*)ga,
                (__attribute__((address_space(3))) void*)&As[(w * 4 + p) * 512], 16, 0, 0);
            __builtin_amdgcn_global_load_lds(
                (const __attribute__((address_space(1))) void*)gb,
                (__attribute__((address_space(3))) void*)&Bs[(w * 4 + p) * 512], 16, 0, 0);
        }
        __syncthreads();

        short8 af[4][2], bfv[4][2];
        #pragma unroll
        for (int m = 0; m < 4; ++m)
            #pragma unroll
            for (int kk = 0; kk < 2; ++kk)
                af[m][kk] = *(const short8*)&As[(wr * 64 + m * 16 + r16) * 64 + kk * 32 + kg * 8];
        #pragma unroll
        for (int n = 0; n < 4; ++n)
            #pragma unroll
            for (int kk = 0; kk < 2; ++kk)
                bfv[n][kk] = *(const short8*)&Bs[(wc * 64 + n * 16 + r16) * 64 + kk * 32 + kg * 8];

        #pragma unroll
        for (int m = 0; m < 4; ++m)
            #pragma unroll
            for (int n = 0; n < 4; ++n)
                #pragma unroll
                for (int kk = 0; kk < 2; ++kk)
                    acc[m][n] = __builtin_amdgcn_mfma_f32_16x16x32_bf16(
                        af[m][kk], bfv[n][kk], acc[m][n], 0, 0, 0);
        __syncthreads();
    }

    // C/D layout: col = lane&15, row = (lane>>4)*4 + reg   [m89/m91 verified]
    #pragma unroll
    for (int m = 0; m < 4; ++m)
        #pragma unroll
        for (int n = 0; n < 4; ++n) {
            int row0 = mbase + wr * 64 + m * 16 + kg * 4;
            int col  = nbase + wc * 64 + n * 16 + r16;
            #pragma unroll
            for (int r = 0; r < 4; ++r)
                C[(size_t)(row0 + r) * NH3 + col] = f2bf(acc[m][n][r]);
        }
}

// ---- passA: per-chunk (prod f, partial c) --------------------------------
__global__ void k_passA(const unsigned short* __restrict__ U, const float* __restrict__ bias,
                        float* __restrict__ P, float* __restrict__ S) {
    int ci = blockIdx.x >> 6;
    int b  = blockIdx.x & 63;
    int h  = threadIdx.x;
    float bfv = bias[h];
    size_t base = ((size_t)(ci * TC) * B_SZ + b) * NH3 + h;
    float c = 0.f, pr = 1.f;
    #pragma unroll 4
    for (int t = 0; t < TC; ++t) {
        float xt = bf2f(U[base]);
        float fr = bf2f(U[base + 256]);
        float f = sigmoidf_(fr + bfv);
        c = f * c + (1.f - f) * xt;
        pr *= f;
        base += (size_t)B_SZ * NH3;
    }
    int o = blockIdx.x * 256 + h;
    P[o] = pr;
    S[o] = c;
}

// ---- passB: sequential chunk-prefix (64 steps), also emits final c -------
__global__ void k_passB(const float* __restrict__ P, const float* __restrict__ S,
                        float* __restrict__ cin) {
    int b = blockIdx.x, h = threadIdx.x;
    int idx = b * 256 + h;
    float c = 0.f;
    #pragma unroll 8
    for (int ci = 0; ci < NC; ++ci) {
        cin[ci * 16384 + idx] = c;
        c = P[ci * 16384 + idx] * c + S[ci * 16384 + idx];
    }
    cin[NC * 16384 + idx] = c;
}

// ---- passC: recompute chunk scan with true c_in, emit h (bf16) -----------
__global__ void k_passC(const unsigned short* __restrict__ U, const float* __restrict__ bias,
                        const unsigned short* __restrict__ xb, const float* __restrict__ cin,
                        unsigned short* __restrict__ hout) {
    int ci = blockIdx.x >> 6, b = blockIdx.x & 63, h = threadIdx.x;
    float bfv = bias[h], brv = bias[256 + h];
    float c = cin[blockIdx.x * 256 + h];
    size_t base  = ((size_t)(ci * TC) * B_SZ + b) * NH3 + h;
    size_t xbase = ((size_t)(ci * TC) * B_SZ + b) * H_SZ + h;
    #pragma unroll 4
    for (int t = 0; t < TC; ++t) {
        float xt = bf2f(U[base]);
        float fr = bf2f(U[base + 256]);
        float rr = bf2f(U[base + 512]);
        float f = sigmoidf_(fr + bfv);
        float r = sigmoidf_(rr + brv);
        c = f * c + (1.f - f) * xt;
        float xv = bf2f(xb[xbase]);
        hout[xbase] = f2bf(r * c + (1.f - r) * xv * SCALE_X_F);
        base  += (size_t)B_SZ * NH3;
        xbase += (size_t)B_SZ * H_SZ;
    }
}

// ---- final: c_{T-1} + r_{T-1} + highway + [64,256]x[256,2] head ----------
__global__ void k_final(const unsigned short* __restrict__ U, const float* __restrict__ bias,
                        const unsigned short* __restrict__ h1, const float* __restrict__ cin,
                        const float* __restrict__ lw, const float* __restrict__ lb,
                        float* __restrict__ out) {
    int b = blockIdx.x, h = threadIdx.x;
    float c = cin[NC * 16384 + b * 256 + h];
    size_t ub = ((size_t)(T_LEN - 1) * B_SZ + b) * NH3;
    float r = sigmoidf_(bf2f(U[ub + 512 + h]) + bias[256 + h]);
    float xl = bf2f(h1[((size_t)(T_LEN - 1) * B_SZ + b) * H_SZ + h]);
    float hv = r * c + (1.f - r) * xl * SCALE_X_F;
    float p0 = hv * lw[h * 2];
    float p1 = hv * lw[h * 2 + 1];
    #pragma unroll
    for (int off = 32; off; off >>= 1) {
        p0 += __shfl_down(p0, off);
        p1 += __shfl_down(p1, off);
    }
    __shared__ float s0[4], s1[4];
    int wid = h >> 6, lane = h & 63;
    if (lane == 0) { s0[wid] = p0; s1[wid] = p1; }
    __syncthreads();
    if (h == 0) {
        out[b * 2]     = s0[0] + s0[1] + s0[2] + s0[3] + lb[0];
        out[b * 2 + 1] = s1[0] + s1[1] + s1[2] + s1[3] + lb[1];
    }
}

extern "C" void kernel_launch(void* const* d_in, const int* in_sizes, int n_in,
                              void* d_out, int out_size, void* d_ws, size_t ws_size,
                              hipStream_t stream) {
    const float* x   = (const float*)d_in[0];
    const float* W1  = (const float*)d_in[1];
    const float* b1  = (const float*)d_in[2];
    const float* W2  = (const float*)d_in[3];
    const float* b2  = (const float*)d_in[4];
    const float* lw  = (const float*)d_in[5];
    const float* lb  = (const float*)d_in[6];
    float* out = (float*)d_out;

    char* ws = (char*)d_ws;
    // U bf16 [131072][768]                      : 201,326,592 B
    // xb bf16 [131072][256]                     :  67,108,864 B
    // h1 bf16 [131072][256]                     :  67,108,864 B
    // Wt1/Wt2 bf16 [768][256]                   :     393,216 B each
    // P, S f32 [64][64][256]                    :   4,194,304 B each
    // cin f32 [65][64][256]                     :   4,259,840 B
    unsigned short* U   = (unsigned short*)ws;
    unsigned short* xb  = (unsigned short*)(ws + 201326592);
    unsigned short* h1  = (unsigned short*)(ws + 268435456);
    unsigned short* Wt1 = (unsigned short*)(ws + 335544320);
    unsigned short* Wt2 = (unsigned short*)(ws + 335937536);
    float* Pbuf = (float*)(ws + 336330752);
    float* Sbuf = (float*)(ws + 340525056);
    float* cin  = (float*)(ws + 344719360);
    // total: 348,979,200 B

    k_convert_x<<<16384, 256, 0, stream>>>(x, xb);
    k_prep_w<<<768, 256, 0, stream>>>(W1, Wt1);
    k_prep_w<<<768, 256, 0, stream>>>(W2, Wt2);

    // layer 1
    k_gemm<<<6144, 256, 0, stream>>>(xb, Wt1, U);
    k_passA<<<4096, 256, 0, stream>>>(U, b1, Pbuf, Sbuf);
    k_passB<<<64, 256, 0, stream>>>(Pbuf, Sbuf, cin);
    k_passC<<<4096, 256, 0, stream>>>(U, b1, xb, cin, h1);

    // layer 2 (only c_{T-1} and r_{T-1} needed)
    k_gemm<<<6144, 256, 0, stream>>>(h1, Wt2, U);
    k_passA<<<4096, 256, 0, stream>>>(U, b2, Pbuf, Sbuf);
    k_passB<<<64, 256, 0, stream>>>(Pbuf, Sbuf, cin);
    k_final<<<64, 256, 0, stream>>>(U, b2, h1, cin, lw, lb, out);
}